// Round 11
// baseline (191.782 us; speedup 1.0000x reference)
//
#include <hip/hip_runtime.h>
#include <math.h>

#define T_LEN   720
#define V_DIM   64
#define KBINS   4
#define NKNOTS  4
#define BLOCK   384     // 6 waves; 16 v-groups x 24 t-phases -> 4 blocks/CU, 24 waves
#define TSLICE  30      // uniform: 720 = 24 * 30
#define NW      6
#define PIPE    4       // rolling prefetch depth

// ws float offsets (kernel A -> kernel B)
#define WS_TAB  0       // [720][8] = {cos k0..3, sin k0..3} per t
#define WS_SR   5760    // [4][64]  Re(scale)-1, [k][v]
#define WS_SI   6016    // [4][64]  Im(scale),   [k][v]
#define WS_KN   6272    // [4][64]  clipped knots, [n][v]

// ---- Kernel A: one-time tables (no transcendentals in kernel B) ----
__global__ __launch_bounds__(256) void precompute_kernel(
    const float* __restrict__ a, const float* __restrict__ phi,
    const float* __restrict__ env_knots, const int* __restrict__ k_bins,
    float* __restrict__ ws)
{
    int id = blockIdx.x * 256 + threadIdx.x;
    if (id < T_LEN * KBINS) {
        int t = id >> 2, k = id & 3;
        int kb = k_bins[k];
        int m  = (kb * t) % T_LEN;                       // exact integer angle reduction
        float th = (float)m * 0.00872664625997164788f;   // 2*pi/720
        float sn, cs;
        sincosf(th, &sn, &cs);
        ws[WS_TAB + t * 8 + k]     = cs;
        ws[WS_TAB + t * 8 + 4 + k] = sn;
    } else if (id < T_LEN * KBINS + V_DIM * KBINS) {
        int e = id - T_LEN * KBINS;                      // v*4+k
        int v = e >> 2, k = e & 3;
        float amp = 1.0f + a[e];
        float ph  = tanhf(phi[e]) * 0.25f;
        float sp, cp;
        sincosf(ph, &sp, &cp);
        ws[WS_SR + k * V_DIM + v] = amp * cp - 1.0f;
        ws[WS_SI + k * V_DIM + v] = amp * sp;
    } else if (id < T_LEN * KBINS + V_DIM * KBINS + V_DIM * NKNOTS) {
        int e = id - T_LEN * KBINS - V_DIM * KBINS;      // v*4+n
        int v = e >> 2, n = e & 3;
        ws[WS_KN + n * V_DIM + v] = fminf(fmaxf(env_knots[e], 0.5f), 1.5f);
    }
}

// ---- Kernel B: one block per b; 4 blocks/CU for phase interleave; 4-deep pipeline ----
__global__ __launch_bounds__(BLOCK) void SeasonalEnvelopeAdapter_kernel(
    const float* __restrict__ y,
    const float* __restrict__ ws,
    float* __restrict__ out)
{
    __shared__ __align__(16) float tab[T_LEN * 8];       // 23,040 B {c0..3,s0..3}/t
    __shared__ float red[16][NW][33];                    // 12,672 B (writer banks 6g%32: distinct)
    __shared__ __align__(16) float coefT[8][V_DIM];      //  2,048 B [k][v] re / [4+k][v] im
    __shared__ __align__(16) float knT[NKNOTS][V_DIM];   //  1,024 B
    // total 38,784 B -> 4 blocks/CU (LDS), 1536 threads/CU

    const int tid  = threadIdx.x;
    const int b    = blockIdx.x;
    const int g    = tid & 15;      // v-group: v0 = 4*g -> 256 B/row coalesced
    const int s    = tid >> 4;      // t-phase 0..23; t = 24*i + s (uniform 30 iters)
    const int lane = tid & 63;
    const int w    = tid >> 6;      // wave 0..5

    // ---- Phase 0: ws tables -> LDS ----
    for (int e = tid; e < 1440; e += BLOCK)
        ((float4*)tab)[e] = ((const float4*)(ws + WS_TAB))[e];
    if (tid < NKNOTS * V_DIM) ((float*)knT)[tid] = ws[WS_KN + tid];
    __syncthreads();

    // ---- Phase 1: stream y (4 loads in flight), accumulate DFT partials ----
    const size_t base = (size_t)b * (T_LEN * V_DIM) + (size_t)(g << 2);
    float accre[4][4], accim[4][4];
    #pragma unroll
    for (int j = 0; j < 4; ++j)
        #pragma unroll
        for (int k = 0; k < 4; ++k) { accre[j][k] = 0.f; accim[j][k] = 0.f; }

    {
        float4 yv[PIPE];
        #pragma unroll
        for (int i0 = 0; i0 < PIPE; ++i0)
            yv[i0] = *(const float4*)(y + base + (size_t)(24 * i0 + s) * V_DIM);
        #pragma unroll
        for (int i = 0; i < TSLICE; ++i) {
            int t = 24 * i + s;
            float4 cur = yv[i & (PIPE - 1)];
            if (i + PIPE < TSLICE)
                yv[i & (PIPE - 1)] = *(const float4*)(y + base + (size_t)(24 * (i + PIPE) + s) * V_DIM);
            float4 c4 = *(const float4*)(&tab[t * 8]);
            float4 s4 = *(const float4*)(&tab[t * 8 + 4]);
            const float cs[4] = {c4.x, c4.y, c4.z, c4.w};
            const float sn[4] = {s4.x, s4.y, s4.z, s4.w};
            const float yj[4] = {cur.x, cur.y, cur.z, cur.w};
            #pragma unroll
            for (int j = 0; j < 4; ++j)
                #pragma unroll
                for (int k = 0; k < 4; ++k) {
                    accre[j][k] = fmaf(yj[j], cs[k], accre[j][k]);
                    accim[j][k] = fmaf(yj[j], sn[k], accim[j][k]);
                }
        }
    }

    // ---- Reduce: shuffle over the wave's 4 s-phases, write per-wave partials ----
    #pragma unroll
    for (int j = 0; j < 4; ++j)
        #pragma unroll
        for (int k = 0; k < 4; ++k) {
            float r = accre[j][k], im = accim[j][k];
            r  += __shfl_xor(r, 16, 64);  r  += __shfl_xor(r, 32, 64);
            im += __shfl_xor(im, 16, 64); im += __shfl_xor(im, 32, 64);
            accre[j][k] = r; accim[j][k] = im;
        }
    if (lane < 16) {   // lane == g
        #pragma unroll
        for (int j = 0; j < 4; ++j)
            #pragma unroll
            for (int k = 0; k < 4; ++k) {
                red[lane][w][j * 8 + k]     = accre[j][k];
                red[lane][w][j * 8 + 4 + k] = accim[j][k];
            }
    }
    __syncthreads();

    // ---- Fused fixed-order sum + (scale-1) transform (deterministic) ----
    if (tid < 256) {
        int v = tid >> 2, k = tid & 3;
        int gg = v >> 2, j = v & 3;
        float cr = 0.f, ci = 0.f;
        #pragma unroll
        for (int ww = 0; ww < NW; ++ww) {
            cr += red[gg][ww][j * 8 + k];
            ci += red[gg][ww][j * 8 + 4 + k];
        }
        float sr = ws[WS_SR + k * V_DIM + v];
        float si = ws[WS_SI + k * V_DIM + v];
        const float sc = 2.0f / (float)T_LEN;
        coefT[k][v]     = (cr * sr + ci * si) * sc;   // Re C * 2/T
        coefT[4 + k][v] = (cr * si - ci * sr) * sc;   // Im C * 2/T
    }
    __syncthreads();

    // ---- Phase 2: re-read y (L2/L3-hot, 4 in flight), reconstruct + envelope ----
    float cre[4][4], cim[4][4];   // [k][j]
    #pragma unroll
    for (int k = 0; k < 4; ++k) {
        float4 r4 = *(const float4*)(&coefT[k][g << 2]);
        float4 i4 = *(const float4*)(&coefT[4 + k][g << 2]);
        cre[k][0] = r4.x; cre[k][1] = r4.y; cre[k][2] = r4.z; cre[k][3] = r4.w;
        cim[k][0] = i4.x; cim[k][1] = i4.y; cim[k][2] = i4.z; cim[k][3] = i4.w;
    }

    const float posScale = 3.0f / 719.0f;
    {
        float4 yv[PIPE];
        #pragma unroll
        for (int i0 = 0; i0 < PIPE; ++i0)
            yv[i0] = *(const float4*)(y + base + (size_t)(24 * i0 + s) * V_DIM);
        #pragma unroll
        for (int i = 0; i < TSLICE; ++i) {
            int t = 24 * i + s;
            float4 cur = yv[i & (PIPE - 1)];
            if (i + PIPE < TSLICE)
                yv[i & (PIPE - 1)] = *(const float4*)(y + base + (size_t)(24 * (i + PIPE) + s) * V_DIM);
            float4 c4 = *(const float4*)(&tab[t * 8]);
            float4 s4 = *(const float4*)(&tab[t * 8 + 4]);
            const float cs[4] = {c4.x, c4.y, c4.z, c4.w};
            const float sn[4] = {s4.x, s4.y, s4.z, s4.w};
            float pos = (float)t * posScale;
            int idx = (int)pos; idx = idx > 2 ? 2 : idx;
            float frac = pos - (float)idx;
            float4 e0v = *(const float4*)(&knT[idx][g << 2]);
            float4 e1v = *(const float4*)(&knT[idx + 1][g << 2]);
            const float e0[4] = {e0v.x, e0v.y, e0v.z, e0v.w};
            const float e1[4] = {e1v.x, e1v.y, e1v.z, e1v.w};
            const float yj[4] = {cur.x, cur.y, cur.z, cur.w};
            float oj[4];
            #pragma unroll
            for (int j = 0; j < 4; ++j) {
                float d = 0.f;
                #pragma unroll
                for (int k = 0; k < 4; ++k)
                    d = fmaf(cre[k][j], cs[k], fmaf(-cim[k][j], sn[k], d));
                float env = fmaf(e1[j] - e0[j], frac, e0[j]);
                oj[j] = (yj[j] + d) * env;
            }
            float4 o; o.x = oj[0]; o.y = oj[1]; o.z = oj[2]; o.w = oj[3];
            *(float4*)(out + base + (size_t)t * V_DIM) = o;
        }
    }
}

extern "C" void kernel_launch(void* const* d_in, const int* in_sizes, int n_in,
                              void* d_out, int out_size, void* d_ws, size_t ws_size,
                              hipStream_t stream) {
    const float* y         = (const float*)d_in[0];
    const float* a         = (const float*)d_in[1];
    const float* phi       = (const float*)d_in[2];
    const float* env_knots = (const float*)d_in[3];
    const int*   k_bins    = (const int*)d_in[4];
    float* out = (float*)d_out;
    float* ws  = (float*)d_ws;

    int B = in_sizes[0] / (T_LEN * V_DIM);
    int ids = T_LEN * KBINS + V_DIM * KBINS + V_DIM * NKNOTS;
    precompute_kernel<<<(ids + 255) / 256, 256, 0, stream>>>(a, phi, env_knots, k_bins, ws);
    SeasonalEnvelopeAdapter_kernel<<<B, BLOCK, 0, stream>>>(y, ws, out);
}

// Round 12
// 180.168 us; speedup vs baseline: 1.0645x; 1.0645x over previous
//
#include <hip/hip_runtime.h>
#include <hip/hip_fp16.h>
#include <math.h>

#define T_LEN   720
#define V_DIM   64
#define KBINS   4
#define NKNOTS  4
#define BLOCK   768     // 12 waves; 16 v-groups x 48 t-phases; TSLICE uniform 15
#define TSLICE  15
#define NW      12
#define PIPE    5       // rolling prefetch depth
#define YLS     33      // ylds row stride in uints (132 B): bank = (t + 2g + c) % 32 -> <=2-way

// ws float offsets (kernel A -> kernel B)
#define WS_TABH 0       // [720] uint4 = 8 fp16 {c0..3,s0..3} per t  (2880 floats)
#define WS_SR   2880    // [4][64] Re(scale)-1, [k][v]
#define WS_SI   3136    // [4][64] Im(scale),   [k][v]
#define WS_KN   3392    // [4][64] clipped knots, [n][v]

__device__ __forceinline__ unsigned f2bf_rne(float f) {
    unsigned u = __float_as_uint(f);
    return (u + 0x7FFFu + ((u >> 16) & 1u)) >> 16;
}
__device__ __forceinline__ float bf2f(unsigned h) {
    return __uint_as_float(h << 16);
}

// ---- Kernel A: one-time tables (fp16-packed trig; no transcendentals in B) ----
__global__ __launch_bounds__(256) void precompute_kernel(
    const float* __restrict__ a, const float* __restrict__ phi,
    const float* __restrict__ env_knots, const int* __restrict__ k_bins,
    float* __restrict__ ws)
{
    int id = blockIdx.x * 256 + threadIdx.x;
    if (id < T_LEN) {
        int t = id;
        __half h[8];
        #pragma unroll
        for (int k = 0; k < 4; ++k) {
            int kb = k_bins[k];
            int m  = (kb * t) % T_LEN;                       // exact integer angle reduction
            float th = (float)m * 0.00872664625997164788f;   // 2*pi/720
            float sn, cs;
            sincosf(th, &sn, &cs);
            h[k]     = __float2half_rn(cs);
            h[4 + k] = __float2half_rn(sn);
        }
        ((uint4*)(ws + WS_TABH))[t] = *(const uint4*)(&h[0]);
    } else if (id < T_LEN + V_DIM * KBINS) {
        int e = id - T_LEN;                                  // v*4+k
        int v = e >> 2, k = e & 3;
        float amp = 1.0f + a[e];
        float ph  = tanhf(phi[e]) * 0.25f;
        float sp, cp;
        sincosf(ph, &sp, &cp);
        ws[WS_SR + k * V_DIM + v] = amp * cp - 1.0f;
        ws[WS_SI + k * V_DIM + v] = amp * sp;
    } else if (id < T_LEN + V_DIM * KBINS + V_DIM * NKNOTS) {
        int e = id - T_LEN - V_DIM * KBINS;                  // v*4+n
        int v = e >> 2, n = e & 3;
        ws[WS_KN + n * V_DIM + v] = fminf(fmaxf(env_knots[e], 0.5f), 1.5f);
    }
}

// ---- Kernel B: one block per b; SINGLE HBM pass (bf16 y in LDS); 5-deep pipeline ----
// LDS 133,952 B -> 1 block/CU, 12 waves = 3/SIMD -> VGPR headroom to ~170 (no spill).
__global__ __launch_bounds__(BLOCK) void SeasonalEnvelopeAdapter_kernel(
    const float* __restrict__ y,
    const float* __restrict__ ws,
    float* __restrict__ out)
{
    __shared__ __align__(16) __half tabh[T_LEN][8];      // 11,520 B {c0..3,s0..3}/t fp16
    __shared__ unsigned int yldsU[T_LEN * YLS];          // 95,040 B bf16 y, 2 v's per uint
    __shared__ float red[16][NW][33];                    // 25,344 B fixed-order reduce
    __shared__ __align__(16) float coefT[8][V_DIM];      //  2,048 B [k][v] re / [4+k][v] im

    const int tid  = threadIdx.x;
    const int b    = blockIdx.x;
    const int g    = tid & 15;      // v-group: v0 = 4*g -> 256 B/row coalesced
    const int s    = tid >> 4;      // t-phase 0..47; t = 48*i + s (uniform 15 iters)
    const int lane = tid & 63;
    const int w    = tid >> 6;      // wave 0..11

    // ---- Phase 0: fp16 trig table -> LDS (pure uint4 copy) ----
    if (tid < T_LEN)
        *(uint4*)(&tabh[tid][0]) = ((const uint4*)(ws + WS_TABH))[tid];
    __syncthreads();

    // ---- Phase 1: stream y once (5 loads in flight), DFT f32, stash bf16 ----
    const size_t base = (size_t)b * (T_LEN * V_DIM) + (size_t)(g << 2);
    float accre[4][4], accim[4][4];
    #pragma unroll
    for (int j = 0; j < 4; ++j)
        #pragma unroll
        for (int k = 0; k < 4; ++k) { accre[j][k] = 0.f; accim[j][k] = 0.f; }

    {
        float4 yv[PIPE];
        #pragma unroll
        for (int i0 = 0; i0 < PIPE; ++i0)
            yv[i0] = *(const float4*)(y + base + (size_t)(48 * i0 + s) * V_DIM);
        #pragma unroll
        for (int i = 0; i < TSLICE; ++i) {
            int t = 48 * i + s;
            float4 cur = yv[i % PIPE];
            if (i + PIPE < TSLICE)
                yv[i % PIPE] = *(const float4*)(y + base + (size_t)(48 * (i + PIPE) + s) * V_DIM);
            // bf16 copy for phase 2 (2 x b32, <=2-way banks)
            yldsU[t * YLS + (g << 1)]     = f2bf_rne(cur.x) | (f2bf_rne(cur.y) << 16);
            yldsU[t * YLS + (g << 1) + 1] = f2bf_rne(cur.z) | (f2bf_rne(cur.w) << 16);
            // trig: one b128 -> 8 fp16
            uint4 hp = *(const uint4*)(&tabh[t][0]);
            const __half* h = (const __half*)&hp;
            const float cs[4] = {__half2float(h[0]), __half2float(h[1]),
                                 __half2float(h[2]), __half2float(h[3])};
            const float sn[4] = {__half2float(h[4]), __half2float(h[5]),
                                 __half2float(h[6]), __half2float(h[7])};
            const float yj[4] = {cur.x, cur.y, cur.z, cur.w};
            #pragma unroll
            for (int j = 0; j < 4; ++j)
                #pragma unroll
                for (int k = 0; k < 4; ++k) {
                    accre[j][k] = fmaf(yj[j], cs[k], accre[j][k]);
                    accim[j][k] = fmaf(yj[j], sn[k], accim[j][k]);
                }
        }
    }

    // ---- Reduce: shuffle over the wave's 4 s-phases, write per-wave partials ----
    #pragma unroll
    for (int j = 0; j < 4; ++j)
        #pragma unroll
        for (int k = 0; k < 4; ++k) {
            float r = accre[j][k], im = accim[j][k];
            r  += __shfl_xor(r, 16, 64);  r  += __shfl_xor(r, 32, 64);
            im += __shfl_xor(im, 16, 64); im += __shfl_xor(im, 32, 64);
            accre[j][k] = r; accim[j][k] = im;
        }
    if (lane < 16) {   // lane == g
        #pragma unroll
        for (int j = 0; j < 4; ++j)
            #pragma unroll
            for (int k = 0; k < 4; ++k) {
                red[lane][w][j * 8 + k]     = accre[j][k];
                red[lane][w][j * 8 + 4 + k] = accim[j][k];
            }
    }
    __syncthreads();

    // ---- Fused fixed-order sum + (scale-1) transform (deterministic) ----
    if (tid < 256) {
        int v = tid >> 2, k = tid & 3;
        int gg = v >> 2, j = v & 3;
        float cr = 0.f, ci = 0.f;
        #pragma unroll
        for (int ww = 0; ww < NW; ++ww) {
            cr += red[gg][ww][j * 8 + k];
            ci += red[gg][ww][j * 8 + 4 + k];
        }
        float sr = ws[WS_SR + k * V_DIM + v];
        float si = ws[WS_SI + k * V_DIM + v];
        const float sc = 2.0f / (float)T_LEN;
        coefT[k][v]     = (cr * sr + ci * si) * sc;   // Re C * 2/T
        coefT[4 + k][v] = (cr * si - ci * sr) * sc;   // Im C * 2/T
    }
    __syncthreads();

    // ---- Phase 2: reconstruct from LDS bf16 + register knots, store ----
    float cre[4][4], cim[4][4];   // [k][j]
    #pragma unroll
    for (int k = 0; k < 4; ++k) {
        float4 r4 = *(const float4*)(&coefT[k][g << 2]);
        float4 i4 = *(const float4*)(&coefT[4 + k][g << 2]);
        cre[k][0] = r4.x; cre[k][1] = r4.y; cre[k][2] = r4.z; cre[k][3] = r4.w;
        cim[k][0] = i4.x; cim[k][1] = i4.y; cim[k][2] = i4.z; cim[k][3] = i4.w;
    }
    float kn0[4], kn1[4], kn2[4], kn3[4];   // knots in registers (L1-cached broadcast)
    {
        float4 a4 = *(const float4*)(ws + WS_KN + 0 * V_DIM + (g << 2));
        float4 b4 = *(const float4*)(ws + WS_KN + 1 * V_DIM + (g << 2));
        float4 c4 = *(const float4*)(ws + WS_KN + 2 * V_DIM + (g << 2));
        float4 d4 = *(const float4*)(ws + WS_KN + 3 * V_DIM + (g << 2));
        kn0[0]=a4.x; kn0[1]=a4.y; kn0[2]=a4.z; kn0[3]=a4.w;
        kn1[0]=b4.x; kn1[1]=b4.y; kn1[2]=b4.z; kn1[3]=b4.w;
        kn2[0]=c4.x; kn2[1]=c4.y; kn2[2]=c4.z; kn2[3]=c4.w;
        kn3[0]=d4.x; kn3[1]=d4.y; kn3[2]=d4.z; kn3[3]=d4.w;
    }

    const float posScale = 3.0f / 719.0f;
    #pragma unroll
    for (int i = 0; i < TSLICE; ++i) {
        int t = 48 * i + s;
        unsigned p0 = yldsU[t * YLS + (g << 1)];
        unsigned p1 = yldsU[t * YLS + (g << 1) + 1];
        const float yj[4] = { bf2f(p0 & 0xFFFFu), bf2f(p0 >> 16),
                              bf2f(p1 & 0xFFFFu), bf2f(p1 >> 16) };
        uint4 hp = *(const uint4*)(&tabh[t][0]);
        const __half* h = (const __half*)&hp;
        const float cs[4] = {__half2float(h[0]), __half2float(h[1]),
                             __half2float(h[2]), __half2float(h[3])};
        const float sn[4] = {__half2float(h[4]), __half2float(h[5]),
                             __half2float(h[6]), __half2float(h[7])};
        float pos = (float)t * posScale;
        int idx = (int)pos; idx = idx > 2 ? 2 : idx;
        float frac = pos - (float)idx;
        float oj[4];
        #pragma unroll
        for (int j = 0; j < 4; ++j) {
            float d = 0.f;
            #pragma unroll
            for (int k = 0; k < 4; ++k)
                d = fmaf(cre[k][j], cs[k], fmaf(-cim[k][j], sn[k], d));
            float e0 = (idx == 0) ? kn0[j] : ((idx == 1) ? kn1[j] : kn2[j]);
            float e1 = (idx == 0) ? kn1[j] : ((idx == 1) ? kn2[j] : kn3[j]);
            float env = fmaf(e1 - e0, frac, e0);
            oj[j] = (yj[j] + d) * env;
        }
        float4 o; o.x = oj[0]; o.y = oj[1]; o.z = oj[2]; o.w = oj[3];
        *(float4*)(out + base + (size_t)t * V_DIM) = o;
    }
}

extern "C" void kernel_launch(void* const* d_in, const int* in_sizes, int n_in,
                              void* d_out, int out_size, void* d_ws, size_t ws_size,
                              hipStream_t stream) {
    const float* y         = (const float*)d_in[0];
    const float* a         = (const float*)d_in[1];
    const float* phi       = (const float*)d_in[2];
    const float* env_knots = (const float*)d_in[3];
    const int*   k_bins    = (const int*)d_in[4];
    float* out = (float*)d_out;
    float* ws  = (float*)d_ws;

    int B = in_sizes[0] / (T_LEN * V_DIM);
    int ids = T_LEN + V_DIM * KBINS + V_DIM * NKNOTS;
    precompute_kernel<<<(ids + 255) / 256, 256, 0, stream>>>(a, phi, env_knots, k_bins, ws);
    SeasonalEnvelopeAdapter_kernel<<<B, BLOCK, 0, stream>>>(y, ws, out);
}